// Round 1
// 1230.895 us; speedup vs baseline: 1.0542x; 1.0542x over previous
//
#include <hip/hip_runtime.h>

// MultiLoRALinear: out = x @ (W + sum_n sc_n*mag_n*(up_n @ down_n))^T + b
// R3: 256x256 8-phase counted-vmcnt GEMM template (see analysis above).

#define B_DIM 4
#define S_DIM 4096
#define IND   4096
#define OUTD  4096
#define NA    8
#define RK    64
#define MROWS (B_DIM * S_DIM)
#define KADAPT (NA * RK)

typedef __attribute__((ext_vector_type(8))) short short8;
typedef __attribute__((ext_vector_type(8))) unsigned short ushort8;
typedef __attribute__((ext_vector_type(4))) float float4v;

__device__ __forceinline__ unsigned short f2bf(float f) {
  unsigned int u = __builtin_bit_cast(unsigned int, f);
  u += 0x7FFFu + ((u >> 16) & 1u);
  return (unsigned short)(u >> 16);
}

__global__ void fold_up_k(const float* __restrict__ ups, const float* __restrict__ mags,
                          const float* __restrict__ scales, unsigned short* __restrict__ up_eff) {
  int tid = blockIdx.x * 256 + threadIdx.x;
  int o  = tid >> 9;
  int nr = tid & 511;
  int n  = nr >> 6;
  int r  = nr & 63;
  float v = ups[((size_t)n * OUTD + o) * RK + r] * mags[n * OUTD + o] * scales[n];
  up_eff[tid] = f2bf(v);
}

__global__ void tdown_k(const float* __restrict__ downs, unsigned short* __restrict__ dT) {
  int tid = blockIdx.x * 256 + threadIdx.x;
  int i  = tid >> 9;
  int nr = tid & 511;
  dT[tid] = f2bf(downs[(size_t)nr * IND + i]);
}

__global__ void cvt_x_k(const float* __restrict__ x, unsigned short* __restrict__ xb) {
  int tid = blockIdx.x * 256 + threadIdx.x;
  const float4v* xv = (const float4v*)x;
  float4v a = xv[2 * tid];
  float4v b = xv[2 * tid + 1];
  ushort8 o;
  o[0] = f2bf(a[0]); o[1] = f2bf(a[1]); o[2] = f2bf(a[2]); o[3] = f2bf(a[3]);
  o[4] = f2bf(b[0]); o[5] = f2bf(b[1]); o[6] = f2bf(b[2]); o[7] = f2bf(b[3]);
  ((ushort8*)xb)[tid] = o;
}

#define GLOAD_LDS16(g, l)                                                        \
  __builtin_amdgcn_global_load_lds((const __attribute__((address_space(1))) void*)(g), \
                                   (__attribute__((address_space(3))) void*)(l), 16, 0, 0)

template <int EPI>
__global__ __launch_bounds__(512, 2) void gemm256(const unsigned short* __restrict__ A,
                                                  const unsigned short* __restrict__ B,
                                                  const float* __restrict__ extra,
                                                  void* __restrict__ Cout,
                                                  int M, int N, int K) {
  __shared__ __align__(16) unsigned short As[2][2][256 * 32];  // 64 KB
  __shared__ __align__(16) unsigned short Bs[2][2][256 * 32];  // 64 KB

  const int tid  = threadIdx.x;
  const int lane = tid & 63;
  const int w    = tid >> 6;
  const int wm   = w >> 2;
  const int wn   = w & 3;
  const int qr   = lane & 15;
  const int q8   = (lane >> 4) * 8;

  const int nwg  = gridDim.x * gridDim.y;
  const int orig = blockIdx.y * gridDim.x + blockIdx.x;
  const int cpx  = nwg >> 3;
  const int swz  = (orig & 7) * cpx + (orig >> 3);
  const int bm   = swz / gridDim.y;
  const int bn   = swz % gridDim.y;

  const size_t Kz = (size_t)K;
  const unsigned short* aSrc = A + ((size_t)bm * 256 + w * 32 + (lane >> 2)) * Kz + (lane & 3) * 8;
  const unsigned short* bSrc = B + ((size_t)bn * 256 + w * 32 + (lane >> 2)) * Kz + (lane & 3) * 8;
  const size_t seg1 = 16 * Kz;

  unsigned short* aBuf = &As[0][0][0];
  unsigned short* bBuf = &Bs[0][0][0];

#define STAGE(SRC, REG)                                 \
  do {                                                  \
    GLOAD_LDS16((SRC), (REG) + w * 1024);               \
    GLOAD_LDS16((SRC) + seg1, (REG) + w * 1024 + 512);  \
  } while (0)

#define LDS_A(REG, MH)                                                                    \
  {                                                                                       \
    _Pragma("unroll") for (int fm = 0; fm < 4; ++fm)                                      \
      a[fm] = *(const short8*)((REG) + (wm * 128 + ((MH) * 4 + fm) * 16 + qr) * 32 + q8); \
  }

#define LDS_B(REG)                                                                        \
  {                                                                                       \
    _Pragma("unroll") for (int fn = 0; fn < 4; ++fn)                                      \
      b[fn] = *(const short8*)((REG) + (wn * 64 + fn * 16 + qr) * 32 + q8);               \
  }

#define MFMA_Q(MH)                                                                        \
  __builtin_amdgcn_sched_barrier(0);                                                      \
  __builtin_amdgcn_s_barrier();                                                           \
  asm volatile("s_waitcnt lgkmcnt(0)" ::: "memory");                                      \
  __builtin_amdgcn_sched_barrier(0);                                                      \
  __builtin_amdgcn_s_setprio(1);                                                          \
  {                                                                                       \
    _Pragma("unroll") for (int fm = 0; fm < 4; ++fm)                                      \
      _Pragma("unroll") for (int fn = 0; fn < 4; ++fn)                                    \
        acc[(MH) * 4 + fm][fn] = __builtin_amdgcn_mfma_f32_16x16x32_bf16(                 \
            a[fm], b[fn], acc[(MH) * 4 + fm][fn], 0, 0, 0);                               \
  }                                                                                       \
  __builtin_amdgcn_s_setprio(0);                                                          \
  __builtin_amdgcn_sched_barrier(0);

  float4v acc[8][4] = {};
  short8 a[4], b[4];

  const int NT = K >> 6;

  STAGE(aSrc, aBuf);
  STAGE(bSrc, bBuf);
  STAGE(aSrc + 32, aBuf + 8192);
  STAGE(bSrc + 32, bBuf + 8192);
  asm volatile("s_waitcnt vmcnt(4)" ::: "memory");
  __builtin_amdgcn_s_barrier();

  for (int t = 0; t < NT - 1; ++t) {
    const int pc = (t & 1) << 14;
    const int pn = pc ^ 16384;
    unsigned short* aCur = aBuf + pc;
    unsigned short* bCur = bBuf + pc;
    unsigned short* aNx  = aBuf + pn;
    unsigned short* bNx  = bBuf + pn;
    const unsigned short* aN = aSrc + 64;
    const unsigned short* bN = bSrc + 64;

    LDS_A(aCur, 0);
    LDS_B(bCur);
    STAGE(aN, aNx);
    MFMA_Q(0);
    __builtin_amdgcn_s_barrier();

    LDS_A(aCur, 1);
    STAGE(bN, bNx);
    MFMA_Q(1);
    asm volatile("s_waitcnt vmcnt(4)" ::: "memory");
    __builtin_amdgcn_s_barrier();

    LDS_A(aCur + 8192, 0);
    LDS_B(bCur + 8192);
    STAGE(aN + 32, aNx + 8192);
    MFMA_Q(0);
    __builtin_amdgcn_s_barrier();

    LDS_A(aCur + 8192, 1);
    STAGE(bN + 32, bNx + 8192);
    MFMA_Q(1);
    asm volatile("s_waitcnt vmcnt(4)" ::: "memory");
    __builtin_amdgcn_s_barrier();

    aSrc = aN;
    bSrc = bN;
  }

  {
    const int pc = ((NT - 1) & 1) << 14;
    unsigned short* aCur = aBuf + pc;
    unsigned short* bCur = bBuf + pc;

    LDS_A(aCur, 0);
    LDS_B(bCur);
    MFMA_Q(0);
    __builtin_amdgcn_s_barrier();

    LDS_A(aCur, 1);
    MFMA_Q(1);
    asm volatile("s_waitcnt vmcnt(0)" ::: "memory");
    __builtin_amdgcn_s_barrier();

    LDS_A(aCur + 8192, 0);
    LDS_B(bCur + 8192);
    MFMA_Q(0);
    __builtin_amdgcn_s_barrier();

    LDS_A(aCur + 8192, 1);
    MFMA_Q(1);
  }

  if (EPI == 0) {
    float* C = (float*)Cout;
#pragma unroll
    for (int fn = 0; fn < 4; ++fn) {
      const int col = bn * 256 + wn * 64 + fn * 16 + qr;
      const float bias = extra[col];
#pragma unroll
      for (int fm = 0; fm < 8; ++fm) {
        const int rbase = bm * 256 + wm * 128 + fm * 16 + (lane >> 4) * 4;
#pragma unroll
        for (int r2 = 0; r2 < 4; ++r2)
          C[(size_t)(rbase + r2) * N + col] = acc[fm][fn][r2] + bias;
      }
    }
  } else {
    unsigned short* C = (unsigned short*)Cout;
#pragma unroll
    for (int fn = 0; fn < 4; ++fn) {
      const int col = bn * 256 + wn * 64 + fn * 16 + qr;
#pragma unroll
      for (int fm = 0; fm < 8; ++fm) {
        const int rbase = bm * 256 + wm * 128 + fm * 16 + (lane >> 4) * 4;
#pragma unroll
        for (int r2 = 0; r2 < 4; ++r2) {
          const size_t idx = (size_t)(rbase + r2) * N + col;
          C[idx] = f2bf(acc[fm][fn][r2] + extra[idx]);
        }
      }
    }
  }

#undef STAGE
#undef LDS_A
#undef LDS_B
#undef MFMA_Q
}

extern "C" void kernel_launch(void* const* d_in, const int* in_sizes, int n_in,
                              void* d_out, int out_size, void* d_ws, size_t ws_size,
                              hipStream_t stream) {
  const float* x      = (const float*)d_in[0];
  const float* W      = (const float*)d_in[1];
  const float* b      = (const float*)d_in[2];
  const float* downs  = (const float*)d_in[3];
  const float* ups    = (const float*)d_in[4];
  const float* mags   = (const float*)d_in[5];
  const float* scales = (const float*)d_in[6];
  float* out = (float*)d_out;

  char* ws = (char*)d_ws;
  unsigned short* x_bf   = (unsigned short*)ws;
  unsigned short* w_eff  = (unsigned short*)(ws + 134217728ull);
  unsigned short* up_eff = (unsigned short*)(ws + 134217728ull + 33554432ull);
  unsigned short* dT     = (unsigned short*)(ws + 134217728ull + 33554432ull + 4194304ull);

  fold_up_k<<<dim3((OUTD * KADAPT) / 256), dim3(256), 0, stream>>>(ups, mags, scales, up_eff);
  tdown_k<<<dim3((IND * KADAPT) / 256), dim3(256), 0, stream>>>(downs, dT);
  cvt_x_k<<<dim3((MROWS * IND / 8) / 256), dim3(256), 0, stream>>>(x, x_bf);

  // W_eff = bf16(W + UpEff @ DownsT)   [OUTD, IND], K=512 (NT=8)
  gemm256<1><<<dim3(OUTD / 256, IND / 256), dim3(512), 0, stream>>>(
      up_eff, dT, W, (void*)w_eff, OUTD, IND, KADAPT);

  // out = x_bf @ W_eff^T + b   [MROWS, OUTD] fp32, K=4096 (NT=64)
  gemm256<0><<<dim3(MROWS / 256, OUTD / 256), dim3(512), 0, stream>>>(
      x_bf, w_eff, b, (void*)out, MROWS, OUTD, IND);
}

// Round 3
// 1196.788 us; speedup vs baseline: 1.0842x; 1.0285x over previous
//
#include <hip/hip_runtime.h>

// MultiLoRALinear: out = x @ (W + sum_n sc_n*mag_n*(up_n @ down_n))^T + b
// R5 == R4 resubmit (R2's bench was an infra failure: container never ran).
// R4: 256x256 8-phase counted-vmcnt GEMM + R2's LDS XOR chunk swizzle
// (slot [row][kq] holds global chunk kq ^ ((row>>1)&3)). R3 regression
// signature: SQ_LDS_BANK_CONFLICT 0 -> 5.0e7, MfmaUtil stuck at 30% -- the
// 64B-row fragment read is an 8-way conflict without the swizzle. Swizzle is
// applied on the GLOBAL source (LDS dest of global_load_lds stays linear)
// and mirrored on the ds_read slot; fragment registers are bit-identical.

#define B_DIM 4
#define S_DIM 4096
#define IND   4096
#define OUTD  4096
#define NA    8
#define RK    64
#define MROWS (B_DIM * S_DIM)
#define KADAPT (NA * RK)

typedef __attribute__((ext_vector_type(8))) short short8;
typedef __attribute__((ext_vector_type(8))) unsigned short ushort8;
typedef __attribute__((ext_vector_type(4))) float float4v;

__device__ __forceinline__ unsigned short f2bf(float f) {
  unsigned int u = __builtin_bit_cast(unsigned int, f);
  u += 0x7FFFu + ((u >> 16) & 1u);
  return (unsigned short)(u >> 16);
}

__global__ void fold_up_k(const float* __restrict__ ups, const float* __restrict__ mags,
                          const float* __restrict__ scales, unsigned short* __restrict__ up_eff) {
  int tid = blockIdx.x * 256 + threadIdx.x;
  int o  = tid >> 9;
  int nr = tid & 511;
  int n  = nr >> 6;
  int r  = nr & 63;
  float v = ups[((size_t)n * OUTD + o) * RK + r] * mags[n * OUTD + o] * scales[n];
  up_eff[tid] = f2bf(v);
}

__global__ void tdown_k(const float* __restrict__ downs, unsigned short* __restrict__ dT) {
  int tid = blockIdx.x * 256 + threadIdx.x;
  int i  = tid >> 9;
  int nr = tid & 511;
  dT[tid] = f2bf(downs[(size_t)nr * IND + i]);
}

__global__ void cvt_x_k(const float* __restrict__ x, unsigned short* __restrict__ xb) {
  int tid = blockIdx.x * 256 + threadIdx.x;
  const float4v* xv = (const float4v*)x;
  float4v a = xv[2 * tid];
  float4v b = xv[2 * tid + 1];
  ushort8 o;
  o[0] = f2bf(a[0]); o[1] = f2bf(a[1]); o[2] = f2bf(a[2]); o[3] = f2bf(a[3]);
  o[4] = f2bf(b[0]); o[5] = f2bf(b[1]); o[6] = f2bf(b[2]); o[7] = f2bf(b[3]);
  ((ushort8*)xb)[tid] = o;
}

#define GLOAD_LDS16(g, l)                                                        \
  __builtin_amdgcn_global_load_lds((const __attribute__((address_space(1))) void*)(g), \
                                   (__attribute__((address_space(3))) void*)(l), 16, 0, 0)

// NT GEMM: C[m,n] = sum_k A[m,k]*B[n,k], A:[M,K] B:[N,K] bf16 row-major.
// BM=BN=256, BK=64 (2 x 32-wide k-slices), 512 threads (8 waves, 2x4).
// LDS region per k-slice: [256][32] bf16 (64B rows). Slot [row][kq] holds
// global 16B chunk kq ^ ((row>>1)&3) -> ds_read_b128 is 2-way-aliased (free).
template <int EPI>
__global__ __launch_bounds__(512, 2) void gemm256(const unsigned short* __restrict__ A,
                                                  const unsigned short* __restrict__ B,
                                                  const float* __restrict__ extra,
                                                  void* __restrict__ Cout,
                                                  int M, int N, int K) {
  __shared__ __align__(16) unsigned short As[2][2][256 * 32];  // 64 KB
  __shared__ __align__(16) unsigned short Bs[2][2][256 * 32];  // 64 KB

  const int tid  = threadIdx.x;
  const int lane = tid & 63;
  const int w    = tid >> 6;
  const int wm   = w >> 2;
  const int wn   = w & 3;
  const int qr   = lane & 15;
  // read-side swizzle: global chunk (lane>>4) of row r sits at slot
  // (lane>>4) ^ ((r>>1)&3);  r mod 16 == qr for every fragment row.
  const int ks   = (((lane >> 4) ^ ((qr >> 1) & 3))) * 8;

  const int nwg  = gridDim.x * gridDim.y;
  const int orig = blockIdx.y * gridDim.x + blockIdx.x;
  const int cpx  = nwg >> 3;
  const int swz  = (orig & 7) * cpx + (orig >> 3);
  const int bm   = swz / gridDim.y;
  const int bn   = swz % gridDim.y;

  const size_t Kz = (size_t)K;
  // stage-side swizzle: lane l writes LDS slot l*16B = [lrow][l&3]; source it
  // from global chunk (l&3) ^ ((lrow>>1)&3) so the slot invariant holds.
  const int lrow = lane >> 2;
  const int lk   = (((lane & 3) ^ ((lrow >> 1) & 3))) * 8;
  const unsigned short* aSrc = A + ((size_t)bm * 256 + w * 32 + lrow) * Kz + lk;
  const unsigned short* bSrc = B + ((size_t)bn * 256 + w * 32 + lrow) * Kz + lk;
  const size_t seg1 = 16 * Kz;

  unsigned short* aBuf = &As[0][0][0];
  unsigned short* bBuf = &Bs[0][0][0];

#define STAGE(SRC, REG)                                 \
  do {                                                  \
    GLOAD_LDS16((SRC), (REG) + w * 1024);               \
    GLOAD_LDS16((SRC) + seg1, (REG) + w * 1024 + 512);  \
  } while (0)

#define LDS_A(REG, MH)                                                                    \
  {                                                                                       \
    _Pragma("unroll") for (int fm = 0; fm < 4; ++fm)                                      \
      a[fm] = *(const short8*)((REG) + (wm * 128 + ((MH) * 4 + fm) * 16 + qr) * 32 + ks); \
  }

#define LDS_B(REG)                                                                        \
  {                                                                                       \
    _Pragma("unroll") for (int fn = 0; fn < 4; ++fn)                                      \
      b[fn] = *(const short8*)((REG) + (wn * 64 + fn * 16 + qr) * 32 + ks);               \
  }

#define MFMA_Q(MH)                                                                        \
  __builtin_amdgcn_sched_barrier(0);                                                      \
  __builtin_amdgcn_s_barrier();                                                           \
  asm volatile("s_waitcnt lgkmcnt(0)" ::: "memory");                                      \
  __builtin_amdgcn_sched_barrier(0);                                                      \
  __builtin_amdgcn_s_setprio(1);                                                          \
  {                                                                                       \
    _Pragma("unroll") for (int fm = 0; fm < 4; ++fm)                                      \
      _Pragma("unroll") for (int fn = 0; fn < 4; ++fn)                                    \
        acc[(MH) * 4 + fm][fn] = __builtin_amdgcn_mfma_f32_16x16x32_bf16(                 \
            a[fm], b[fn], acc[(MH) * 4 + fm][fn], 0, 0, 0);                               \
  }                                                                                       \
  __builtin_amdgcn_s_setprio(0);                                                          \
  __builtin_amdgcn_sched_barrier(0);

  float4v acc[8][4] = {};
  short8 a[4], b[4];

  const int NT = K >> 6;

  // prologue: tile 0 fully staged into buf0; k-hi's 4 loads stay in flight
  STAGE(aSrc, aBuf);
  STAGE(bSrc, bBuf);
  STAGE(aSrc + 32, aBuf + 8192);
  STAGE(bSrc + 32, bBuf + 8192);
  asm volatile("s_waitcnt vmcnt(4)" ::: "memory");
  __builtin_amdgcn_s_barrier();

  // steady-state ledger (per thread): enter tile with 4 in flight (t.khi).
  // ph1 +2 (t+1.A.klo)=6, ph2 +2 (t+1.B.klo)=8 -> vmcnt(4) drains t.khi
  // before ph3 reads it. ph3 +2 =6, ph4 +2 =8 -> vmcnt(4) drains t+1.klo
  // before next tile's ph1. Never 0 until the tail.
  for (int t = 0; t < NT - 1; ++t) {
    const int pc = (t & 1) << 14;
    const int pn = pc ^ 16384;
    unsigned short* aCur = aBuf + pc;
    unsigned short* bCur = bBuf + pc;
    unsigned short* aNx  = aBuf + pn;
    unsigned short* bNx  = bBuf + pn;
    const unsigned short* aN = aSrc + 64;
    const unsigned short* bN = bSrc + 64;

    LDS_A(aCur, 0);
    LDS_B(bCur);
    STAGE(aN, aNx);
    MFMA_Q(0);
    __builtin_amdgcn_s_barrier();

    LDS_A(aCur, 1);
    STAGE(bN, bNx);
    MFMA_Q(1);
    asm volatile("s_waitcnt vmcnt(4)" ::: "memory");
    __builtin_amdgcn_s_barrier();

    LDS_A(aCur + 8192, 0);
    LDS_B(bCur + 8192);
    STAGE(aN + 32, aNx + 8192);
    MFMA_Q(0);
    __builtin_amdgcn_s_barrier();

    LDS_A(aCur + 8192, 1);
    STAGE(bN + 32, bNx + 8192);
    MFMA_Q(1);
    asm volatile("s_waitcnt vmcnt(4)" ::: "memory");
    __builtin_amdgcn_s_barrier();

    aSrc = aN;
    bSrc = bN;
  }

  // tail tile: no staging
  {
    const int pc = ((NT - 1) & 1) << 14;
    unsigned short* aCur = aBuf + pc;
    unsigned short* bCur = bBuf + pc;

    LDS_A(aCur, 0);
    LDS_B(bCur);
    MFMA_Q(0);
    __builtin_amdgcn_s_barrier();

    LDS_A(aCur, 1);
    MFMA_Q(1);
    asm volatile("s_waitcnt vmcnt(0)" ::: "memory");
    __builtin_amdgcn_s_barrier();

    LDS_A(aCur + 8192, 0);
    LDS_B(bCur + 8192);
    MFMA_Q(0);
    __builtin_amdgcn_s_barrier();

    LDS_A(aCur + 8192, 1);
    MFMA_Q(1);
  }

  // epilogue: C/D layout col = lane&15, row = (lane>>4)*4 + reg
  if (EPI == 0) {
    float* C = (float*)Cout;
#pragma unroll
    for (int fn = 0; fn < 4; ++fn) {
      const int col = bn * 256 + wn * 64 + fn * 16 + qr;
      const float bias = extra[col];
#pragma unroll
      for (int fm = 0; fm < 8; ++fm) {
        const int rbase = bm * 256 + wm * 128 + fm * 16 + (lane >> 4) * 4;
#pragma unroll
        for (int r2 = 0; r2 < 4; ++r2)
          C[(size_t)(rbase + r2) * N + col] = acc[fm][fn][r2] + bias;
      }
    }
  } else {
    unsigned short* C = (unsigned short*)Cout;
#pragma unroll
    for (int fn = 0; fn < 4; ++fn) {
      const int col = bn * 256 + wn * 64 + fn * 16 + qr;
#pragma unroll
      for (int fm = 0; fm < 8; ++fm) {
        const int rbase = bm * 256 + wm * 128 + fm * 16 + (lane >> 4) * 4;
#pragma unroll
        for (int r2 = 0; r2 < 4; ++r2) {
          const size_t idx = (size_t)(rbase + r2) * N + col;
          C[idx] = f2bf(acc[fm][fn][r2] + extra[idx]);
        }
      }
    }
  }

#undef STAGE
#undef LDS_A
#undef LDS_B
#undef MFMA_Q
}

extern "C" void kernel_launch(void* const* d_in, const int* in_sizes, int n_in,
                              void* d_out, int out_size, void* d_ws, size_t ws_size,
                              hipStream_t stream) {
  const float* x      = (const float*)d_in[0];
  const float* W      = (const float*)d_in[1];
  const float* b      = (const float*)d_in[2];
  const float* downs  = (const float*)d_in[3];
  const float* ups    = (const float*)d_in[4];
  const float* mags   = (const float*)d_in[5];
  const float* scales = (const float*)d_in[6];
  float* out = (float*)d_out;

  char* ws = (char*)d_ws;
  unsigned short* x_bf   = (unsigned short*)ws;
  unsigned short* w_eff  = (unsigned short*)(ws + 134217728ull);
  unsigned short* up_eff = (unsigned short*)(ws + 134217728ull + 33554432ull);
  unsigned short* dT     = (unsigned short*)(ws + 134217728ull + 33554432ull + 4194304ull);

  fold_up_k<<<dim3((OUTD * KADAPT) / 256), dim3(256), 0, stream>>>(ups, mags, scales, up_eff);
  tdown_k<<<dim3((IND * KADAPT) / 256), dim3(256), 0, stream>>>(downs, dT);
  cvt_x_k<<<dim3((MROWS * IND / 8) / 256), dim3(256), 0, stream>>>(x, x_bf);

  // W_eff = bf16(W + UpEff @ DownsT)   [OUTD, IND], K=512 (NT=8)
  gemm256<1><<<dim3(OUTD / 256, IND / 256), dim3(512), 0, stream>>>(
      up_eff, dT, W, (void*)w_eff, OUTD, IND, KADAPT);

  // out = x_bf @ W_eff^T + b   [MROWS, OUTD] fp32, K=4096 (NT=64)
  gemm256<0><<<dim3(MROWS / 256, OUTD / 256), dim3(512), 0, stream>>>(
      x_bf, w_eff, b, (void*)out, MROWS, OUTD, IND);
}